// Round 1
// baseline (2438.971 us; speedup 1.0000x reference)
//
#include <hip/hip_runtime.h>
#include <stdint.h>

#define NN    10000
#define EE    100000
#define DIN   64
#define HDIM  64
#define EIN   16
#define EH    128
#define HH    4096   // HDIM*HDIM
#define STEPS 3

typedef short bf16x8 __attribute__((ext_vector_type(8)));
typedef float f32x4  __attribute__((ext_vector_type(4)));

__device__ __forceinline__ unsigned short f32_to_bf16(float f) {
    union { float f; uint32_t u; } v; v.f = f;
    uint32_t r = v.u + 0x7fffu + ((v.u >> 16) & 1u);   // RNE
    return (unsigned short)(r >> 16);
}
__device__ __forceinline__ float bf16_lo(uint32_t u) {
    union { uint32_t u; float f; } v; v.u = u << 16; return v.f;
}
__device__ __forceinline__ float bf16_hi(uint32_t u) {
    union { uint32_t u; float f; } v; v.u = u & 0xffff0000u; return v.f;
}

// out[n,o] = relu(n_feat[n,:] @ W0[:,o] + b0[o]); one wave per node
__global__ void k_node_mlp(const float* __restrict__ nf, const float* __restrict__ W0,
                           const float* __restrict__ b0, float* __restrict__ out, int n_nodes) {
    __shared__ float w0s[DIN * HDIM];
    int tid = threadIdx.x;
    for (int i = tid; i < DIN * HDIM; i += 256) w0s[i] = W0[i];
    __syncthreads();
    int node = blockIdx.x * 4 + (tid >> 6);
    int o = tid & 63;
    if (node >= n_nodes) return;
    float xr = nf[node * DIN + o];   // lane o holds x[o]
    float acc = b0[o];
#pragma unroll 8
    for (int i = 0; i < DIN; ++i)
        acc += __shfl(xr, i, 64) * w0s[i * HDIM + o];
    out[node * HDIM + o] = fmaxf(acc, 0.f);
}

// h[e,c] = relu(e_feat[e,:] @ We1[:,c] + be1[c]) -> bf16; 2 edges per 256-block
__global__ void k_edge_mlp(const float* __restrict__ ef, const float* __restrict__ We1,
                           const float* __restrict__ be1, unsigned short* __restrict__ h, int n_edges) {
    int tid = threadIdx.x;
    int e = blockIdx.x * 2 + (tid >> 7);
    int c = tid & 127;
    if (e >= n_edges) return;
    float acc = be1[c];
    const float* x = ef + e * EIN;
#pragma unroll
    for (int i = 0; i < EIN; ++i) acc += x[i] * We1[i * EH + c];
    h[(size_t)e * EH + c] = f32_to_bf16(fmaxf(acc, 0.f));
}

// We2T[n,k] = bf16(We2[k,n])  (so MFMA B-fragments load 16B contiguous)
__global__ void k_we2t(const float* __restrict__ We2, unsigned short* __restrict__ We2T) {
    int t = blockIdx.x * 256 + threadIdx.x;
    if (t >= EH * HH) return;
    int k = t >> 12, n = t & 4095;
    We2T[n * EH + k] = f32_to_bf16(We2[t]);
}

// w_edge[e - e0, c] = bf16( h[e,:] @ We2[:,c] + be2[c] )  via 16x16x32 bf16 MFMA
// wg: 64 edges x 256 cols; wave w: 64 edges x 64 cols (4x4 tiles)
__global__ void k_wedge_gemm(const unsigned short* __restrict__ h, const unsigned short* __restrict__ We2T,
                             const float* __restrict__ be2, unsigned short* __restrict__ wout,
                             int e0, int cnt, int n_edges_tot) {
    int wave = threadIdx.x >> 6;
    int lane = threadIdx.x & 63;
    int r = lane & 15, q = lane >> 4;
    int eb = e0 + blockIdx.x * 64;
    int cb = blockIdx.y * 256 + wave * 64;
    f32x4 acc[4][4] = {};
#pragma unroll
    for (int s = 0; s < 4; ++s) {            // K = 128 = 4 * 32
        bf16x8 afr[4], bfr[4];
#pragma unroll
        for (int mt = 0; mt < 4; ++mt) {
            int e = eb + mt * 16 + r;
            if (e >= n_edges_tot) e = n_edges_tot - 1;
            afr[mt] = *(const bf16x8*)(h + (size_t)e * EH + s * 32 + q * 8);
        }
#pragma unroll
        for (int nt = 0; nt < 4; ++nt) {
            int c = cb + nt * 16 + r;
            bfr[nt] = *(const bf16x8*)(We2T + (size_t)c * EH + s * 32 + q * 8);
        }
#pragma unroll
        for (int mt = 0; mt < 4; ++mt)
#pragma unroll
            for (int nt = 0; nt < 4; ++nt)
                acc[mt][nt] = __builtin_amdgcn_mfma_f32_16x16x32_bf16(afr[mt], bfr[nt], acc[mt][nt], 0, 0, 0);
    }
    int e_end = e0 + cnt; if (e_end > n_edges_tot) e_end = n_edges_tot;
#pragma unroll
    for (int mt = 0; mt < 4; ++mt) {
#pragma unroll
        for (int rg = 0; rg < 4; ++rg) {
            int e = eb + mt * 16 + q * 4 + rg;    // C/D: col=lane&15, row=quad*4+reg
            if (e >= e_end) continue;
            size_t rowoff = (size_t)(e - e0) * HH;
#pragma unroll
            for (int nt = 0; nt < 4; ++nt) {
                int c = cb + nt * 16 + r;
                wout[rowoff + c] = f32_to_bf16(acc[mt][nt][rg] + be2[c]);
            }
        }
    }
}

// per edge: msg[o] = sum_i x[src[e]][i] * w[e][i*64+o]; atomicAdd into agg[dst[e]]
// one wave per edge; lane reads uint4 (8 bf16) -> wave reads 1KiB contiguous/instr
__global__ void k_msg_scatter(const float* __restrict__ out, const unsigned short* __restrict__ w,
                              const int* __restrict__ src, const int* __restrict__ dst,
                              float* __restrict__ agg, int e0, int cnt) {
    int wave = threadIdx.x >> 6;
    int lane = threadIdx.x & 63;
    int idx = blockIdx.x * 4 + wave;
    if (idx >= cnt) return;
    int e = e0 + idx;
    float xv = out[(size_t)src[e] * HDIM + lane];   // lane holds x[lane]
    const uint4* wrow = (const uint4*)(w + (size_t)idx * HH);
    int a = lane >> 3, b = lane & 7;
    float acc[8] = {0,0,0,0,0,0,0,0};
#pragma unroll
    for (int t = 0; t < 8; ++t) {
        uint4 pk = wrow[t * 64 + lane];   // covers c = t*512 + lane*8 .. +7 -> i = t*8+a, o = b*8+j
        float xi = __shfl(xv, t * 8 + a, 64);
        acc[0] += xi * bf16_lo(pk.x); acc[1] += xi * bf16_hi(pk.x);
        acc[2] += xi * bf16_lo(pk.y); acc[3] += xi * bf16_hi(pk.y);
        acc[4] += xi * bf16_lo(pk.z); acc[5] += xi * bf16_hi(pk.z);
        acc[6] += xi * bf16_lo(pk.w); acc[7] += xi * bf16_hi(pk.w);
    }
    // reduce over i-groups: lanes differing in bits 3..5 (same b)
#pragma unroll
    for (int m = 8; m <= 32; m <<= 1)
#pragma unroll
        for (int j = 0; j < 8; ++j)
            acc[j] += __shfl_xor(acc[j], m, 64);
    if (a == 0) {
        float* base = agg + (size_t)dst[e] * HDIM + b * 8;
#pragma unroll
        for (int j = 0; j < 8; ++j) atomicAdd(base + j, acc[j]);
    }
}

__global__ void k_relu_bias(const float* __restrict__ agg, const float* __restrict__ cb,
                            float* __restrict__ out, int n) {
    int t = blockIdx.x * 256 + threadIdx.x;
    if (t >= n) return;
    out[t] = fmaxf(agg[t] + cb[t & 63], 0.f);
}

// grid MUST be 64 blocks (row stride 256 hardcoded)
__global__ void k_bn_stats(const float* __restrict__ out, float* __restrict__ stat, int n_nodes) {
    __shared__ float s1[256], s2[256];
    int tid = threadIdx.x;
    int f = tid & 63, g = tid >> 6;
    float sum = 0.f, ss = 0.f;
    for (int r = blockIdx.x * 4 + g; r < n_nodes; r += 256) {
        float v = out[r * HDIM + f];
        sum += v; ss += v * v;
    }
    s1[tid] = sum; s2[tid] = ss;
    __syncthreads();
    if (tid < 64) {
        float A = s1[tid] + s1[64 + tid] + s1[128 + tid] + s1[192 + tid];
        float B = s2[tid] + s2[64 + tid] + s2[128 + tid] + s2[192 + tid];
        atomicAdd(&stat[tid], A);
        atomicAdd(&stat[64 + tid], B);
    }
}

__global__ void k_bn_final(const float* __restrict__ stat, const float* __restrict__ gamma,
                           const float* __restrict__ beta, float* __restrict__ sc, int n_nodes) {
    int f = threadIdx.x;
    if (f >= 64) return;
    float mean = stat[f] / n_nodes;
    float var  = stat[64 + f] / n_nodes - mean * mean;   // population var (ddof=0)
    float inv  = rsqrtf(var + 1e-5f);
    float scale = gamma[f] * inv;
    sc[f] = scale;
    sc[64 + f] = beta[f] - mean * scale;
}

__global__ void k_bn_apply(const float* __restrict__ out, const float* __restrict__ sc,
                           float* __restrict__ y, int n) {
    int t = blockIdx.x * 256 + threadIdx.x;
    if (t >= n) return;
    int f = t & 63;
    y[t] = out[t] * sc[f] + sc[64 + f];
}

extern "C" void kernel_launch(void* const* d_in, const int* in_sizes, int n_in,
                              void* d_out, int out_size, void* d_ws, size_t ws_size,
                              hipStream_t stream) {
    const float* nf    = (const float*)d_in[0];
    const float* ef    = (const float*)d_in[1];
    const int*   src   = (const int*)d_in[2];
    const int*   dst   = (const int*)d_in[3];
    const float* W0    = (const float*)d_in[4];
    const float* b0    = (const float*)d_in[5];
    const float* We1   = (const float*)d_in[6];
    const float* be1   = (const float*)d_in[7];
    const float* We2   = (const float*)d_in[8];
    const float* be2   = (const float*)d_in[9];
    const float* cbias = (const float*)d_in[10];
    const float* gamma = (const float*)d_in[11];
    const float* beta  = (const float*)d_in[12];
    (void)n_in; (void)out_size;

    int n_nodes = in_sizes[0] / DIN;   // 10000
    int n_edges = in_sizes[2];         // 100000

    char* ws = (char*)d_ws;
    size_t off = 0;
    auto carve = [&](size_t bytes) -> void* {
        void* p = ws + off;
        off = (off + bytes + 255) & ~(size_t)255;
        return p;
    };
    float*          outb = (float*)carve((size_t)n_nodes * HDIM * 4);
    float*          agg  = (float*)carve((size_t)n_nodes * HDIM * 4);
    unsigned short* h    = (unsigned short*)carve((size_t)n_edges * EH * 2);
    unsigned short* We2T = (unsigned short*)carve((size_t)HH * EH * 2);
    float*          stat = (float*)carve(128 * 4);
    float*          sc   = (float*)carve(128 * 4);
    unsigned short* wbuf = (unsigned short*)(ws + off);
    size_t avail = ws_size > off ? ws_size - off : 0;
    long chunk = (long)(avail / ((size_t)HH * 2));   // edges worth of w_edge that fit
    if (chunk > n_edges) chunk = n_edges;
    if (chunk < n_edges) chunk &= ~63L;              // gemm tile multiple
    if (chunk < 64) chunk = 64;                      // last-resort guard
    bool full = (chunk >= n_edges);

    hipMemsetAsync(stat, 0, 128 * 4, stream);
    k_node_mlp<<<dim3((n_nodes + 3) / 4), 256, 0, stream>>>(nf, W0, b0, outb, n_nodes);
    k_edge_mlp<<<dim3((n_edges + 1) / 2), 256, 0, stream>>>(ef, We1, be1, h, n_edges);
    k_we2t<<<dim3((EH * HH + 255) / 256), 256, 0, stream>>>(We2, We2T);

    if (full)
        k_wedge_gemm<<<dim3((n_edges + 63) / 64, HH / 256), 256, 0, stream>>>(
            h, We2T, be2, wbuf, 0, n_edges, n_edges);

    for (int step = 0; step < STEPS; ++step) {
        hipMemsetAsync(agg, 0, (size_t)n_nodes * HDIM * 4, stream);
        if (full) {
            k_msg_scatter<<<dim3((n_edges + 3) / 4), 256, 0, stream>>>(
                outb, wbuf, src, dst, agg, 0, n_edges);
        } else {
            for (long e0 = 0; e0 < n_edges; e0 += chunk) {
                long cnt = (n_edges - e0 < chunk) ? (n_edges - e0) : chunk;
                k_wedge_gemm<<<dim3((cnt + 63) / 64, HH / 256), 256, 0, stream>>>(
                    h, We2T, be2, wbuf, (int)e0, (int)cnt, n_edges);
                k_msg_scatter<<<dim3((cnt + 3) / 4), 256, 0, stream>>>(
                    outb, wbuf, src, dst, agg, (int)e0, (int)cnt);
            }
        }
        k_relu_bias<<<dim3((n_nodes * HDIM + 255) / 256), 256, 0, stream>>>(
            agg, cbias, outb, n_nodes * HDIM);
    }

    k_bn_stats<<<dim3(64), 256, 0, stream>>>(outb, stat, n_nodes);
    k_bn_final<<<dim3(1), 64, 0, stream>>>(stat, gamma, beta, sc, n_nodes);
    k_bn_apply<<<dim3((n_nodes * HDIM + 255) / 256), 256, 0, stream>>>(
        outb, sc, (float*)d_out, n_nodes * HDIM);
}

// Round 3
// 1070.476 us; speedup vs baseline: 2.2784x; 2.2784x over previous
//
#include <hip/hip_runtime.h>
#include <stdint.h>

#define DIN   64
#define HDIM  64
#define EIN   16
#define EHID  128     // edge hidden width
#define HH    4096    // HDIM*HDIM
#define TC    8256    // T columns: 8192 (k*64+o) + 64 bias cols (x@be2-term)
#define STEPS 3

typedef short bf16x8 __attribute__((ext_vector_type(8)));
typedef float f32x4  __attribute__((ext_vector_type(4)));

__device__ __forceinline__ unsigned short f32_to_bf16(float f) {
    union { float f; uint32_t u; } v; v.f = f;
    uint32_t r = v.u + 0x7fffu + ((v.u >> 16) & 1u);   // RNE
    return (unsigned short)(r >> 16);
}
__device__ __forceinline__ float bfu_to_f(unsigned short u) {
    union { uint32_t u; float f; } v; v.u = (uint32_t)u << 16; return v.f;
}
__device__ __forceinline__ float bf16_lo(uint32_t u) {
    union { uint32_t u; float f; } v; v.u = u << 16; return v.f;
}
__device__ __forceinline__ float bf16_hi(uint32_t u) {
    union { uint32_t u; float f; } v; v.u = u & 0xffff0000u; return v.f;
}

// out[n,o] = relu(n_feat[n,:]@W0[:,o]+b0[o]); writes f32 + bf16 copies
__global__ void k_node_mlp(const float* __restrict__ nf, const float* __restrict__ W0,
                           const float* __restrict__ b0, float* __restrict__ outb,
                           unsigned short* __restrict__ outbf, int n_nodes) {
    __shared__ float w0s[DIN * HDIM];
    int tid = threadIdx.x;
    for (int i = tid; i < DIN * HDIM; i += 256) w0s[i] = W0[i];
    __syncthreads();
    int node = blockIdx.x * 4 + (tid >> 6);
    int o = tid & 63;
    if (node >= n_nodes) return;
    float xr = nf[node * DIN + o];
    float acc = b0[o];
#pragma unroll 8
    for (int i = 0; i < DIN; ++i)
        acc += __shfl(xr, i, 64) * w0s[i * HDIM + o];
    float v = fmaxf(acc, 0.f);
    outb[node * HDIM + o] = v;
    outbf[node * HDIM + o] = f32_to_bf16(v);
}

// h[e,c] = relu(e_feat[e,:]@We1[:,c]+be1[c]) -> f32 (precision: keep h exact-ish)
__global__ void k_edge_mlp(const float* __restrict__ ef, const float* __restrict__ We1,
                           const float* __restrict__ be1, float* __restrict__ h, int n_edges) {
    int tid = threadIdx.x;
    int e = blockIdx.x * 2 + (tid >> 7);
    int c = tid & 127;
    if (e >= n_edges) return;
    float acc = be1[c];
    const float* x = ef + (size_t)e * EIN;
#pragma unroll
    for (int i = 0; i < EIN; ++i) acc += x[i] * We1[i * EHID + c];
    h[(size_t)e * EHID + c] = acc > 0.f ? acc : 0.f;
}

// BmatT[c_mfma][i] with column permutation baked in:
// mfma-col c within its 64-group g=c&63 (g = nt*16+r) maps to memory col 4r+nt,
// so the k_T epilogue can pack 4 nt-values into one ushort4 store.
// semantic col m: m<8192 -> B[i][m]=We2[m>>6][i*64+(m&63)]; m>=8192 -> be2[i*64+(m&63)]
__global__ void k_bmat(const float* __restrict__ We2, const float* __restrict__ be2,
                       unsigned short* __restrict__ BmatT) {
    int t = blockIdx.x * 256 + threadIdx.x;
    if (t >= TC * 64) return;
    int c = t >> 6, i = t & 63;
    int g = c & 63;
    int m = (c & ~63) + 4 * (g & 15) + (g >> 4);
    float v = (m < 8192) ? We2[(m >> 6) * HH + i * 64 + (m & 63)]
                         : be2[i * 64 + (m & 63)];
    BmatT[t] = f32_to_bf16(v);
}

// T[n, m] = sum_i x[n,i]*B[i,m], bf16 out, natural layout m = k*64+o (+bias block).
// wg: 64 nodes x 256 cols; wave: 64x64 via 4x4 16x16x32 bf16 MFMA tiles.
// Epilogue: lane packs nt=0..3 (mem cols cb+4r..cb+4r+3) into one 8-B store.
__global__ void k_T(const unsigned short* __restrict__ outbf, const unsigned short* __restrict__ BmatT,
                    unsigned short* __restrict__ T, int n0, int n1) {
    int wave = threadIdx.x >> 6, lane = threadIdx.x & 63;
    int r = lane & 15, q = lane >> 4;
    int eb = n0 + blockIdx.x * 64;
    int cb = blockIdx.y * 256 + wave * 64;
    f32x4 acc[4][4] = {};
#pragma unroll
    for (int s = 0; s < 2; ++s) {            // K = 64 = 2*32
        bf16x8 afr[4], bfr[4];
#pragma unroll
        for (int mt = 0; mt < 4; ++mt) {
            int e = eb + mt * 16 + r;
            if (e >= n1) e = n1 - 1;
            afr[mt] = *(const bf16x8*)(outbf + (size_t)e * 64 + s * 32 + q * 8);
        }
#pragma unroll
        for (int nt = 0; nt < 4; ++nt) {
            int c = cb + nt * 16 + r;
            if (c >= TC) c = 0;              // clamped load; store guarded
            bfr[nt] = *(const bf16x8*)(BmatT + (size_t)c * 64 + s * 32 + q * 8);
        }
#pragma unroll
        for (int mt = 0; mt < 4; ++mt)
#pragma unroll
            for (int nt = 0; nt < 4; ++nt)
                acc[mt][nt] = __builtin_amdgcn_mfma_f32_16x16x32_bf16(afr[mt], bfr[nt], acc[mt][nt], 0, 0, 0);
    }
    if (cb >= TC) return;                    // whole 64-group out of range
#pragma unroll
    for (int mt = 0; mt < 4; ++mt)
#pragma unroll
        for (int rg = 0; rg < 4; ++rg) {
            int n = eb + mt * 16 + q * 4 + rg;     // C/D: col=lane&15, row=quad*4+reg
            if (n >= n1) continue;
            ushort4 pk;
            pk.x = f32_to_bf16(acc[mt][0][rg]);
            pk.y = f32_to_bf16(acc[mt][1][rg]);
            pk.z = f32_to_bf16(acc[mt][2][rg]);
            pk.w = f32_to_bf16(acc[mt][3][rg]);
            *(ushort4*)(T + (size_t)(n - n0) * TC + cb + 4 * r) = pk;
        }
}

// histogram src and dst
__global__ void k_hist(const int* __restrict__ src, const int* __restrict__ dst,
                       int* __restrict__ cntS, int* __restrict__ cntD, int n_edges) {
    int e = blockIdx.x * 256 + threadIdx.x;
    if (e >= n_edges) return;
    atomicAdd(&cntS[src[e]], 1);
    atomicAdd(&cntD[dst[e]], 1);
}

// exclusive prefix sum (one block per array; blockIdx.x: 0=S, 1=D)
__global__ void k_scan(const int* __restrict__ cntS, const int* __restrict__ cntD,
                       int* __restrict__ offS, int* __restrict__ offD,
                       int* __restrict__ curS, int* __restrict__ curD, int n, int total) {
    const int* cnt = blockIdx.x ? cntD : cntS;
    int* off = blockIdx.x ? offD : offS;
    int* cur = blockIdx.x ? curD : curS;
    __shared__ int part[256];
    int tid = threadIdx.x;
    int chunk = (n + 255) / 256;
    int c0 = tid * chunk, c1 = c0 + chunk; if (c1 > n) c1 = n; if (c0 > n) c0 = n;
    int s = 0;
    for (int i = c0; i < c1; ++i) s += cnt[i];
    part[tid] = s;
    __syncthreads();
    for (int st = 1; st < 256; st <<= 1) {
        int v = (tid >= st) ? part[tid - st] : 0;
        __syncthreads();
        part[tid] += v;
        __syncthreads();
    }
    int run = tid ? part[tid - 1] : 0;
    for (int i = c0; i < c1; ++i) { off[i] = run; cur[i] = run; run += cnt[i]; }
    if (tid == 0) off[n] = total;
}

__global__ void k_perm(const int* __restrict__ src, const int* __restrict__ dst,
                       int* __restrict__ curS, int* __restrict__ curD,
                       int* __restrict__ permS, int* __restrict__ permD, int n_edges) {
    int e = blockIdx.x * 256 + threadIdx.x;
    if (e >= n_edges) return;
    permS[atomicAdd(&curS[src[e]], 1)] = e;
    permD[atomicAdd(&curD[dst[e]], 1)] = e;
}

// per src-node wave: msg[e,o] = sum_k h[e,k]*T[n,k*64+o] + T[n,8192+o]
// lane: p=lane>>4 handles k%4==p, o4=(lane&15)*4
__global__ void k_msg(const float* __restrict__ h, const unsigned short* __restrict__ T,
                      const int* __restrict__ offS, const int* __restrict__ permS,
                      float* __restrict__ msg, int n0, int n1) {
    int wave = threadIdx.x >> 6, lane = threadIdx.x & 63;
    int n = n0 + blockIdx.x * 4 + wave;
    if (n >= n1) return;
    int beg = offS[n], end = offS[n + 1];
    if (beg == end) return;
    int p = lane >> 4, o4 = (lane & 15) * 4;
    const unsigned short* Tb = T + (size_t)(n - n0) * TC;
    for (int j0 = beg; j0 < end; j0 += 4) {
        int e[4]; float hlo[4], hhi[4];
        f32x4 acc[4] = {};
#pragma unroll
        for (int jj = 0; jj < 4; ++jj) {
            int jc = (j0 + jj < end) ? j0 + jj : end - 1;
            e[jj] = permS[jc];
            hlo[jj] = h[(size_t)e[jj] * EHID + lane];
            hhi[jj] = h[(size_t)e[jj] * EHID + 64 + lane];
        }
#pragma unroll
        for (int i = 0; i < 16; ++i) {       // k = 4*i + p, k < 64
            uint2 pk = *(const uint2*)(Tb + i * 256 + p * 64 + o4);
            f32x4 t4 = { bf16_lo(pk.x), bf16_hi(pk.x), bf16_lo(pk.y), bf16_hi(pk.y) };
            int ks = i * 4 + p;
#pragma unroll
            for (int jj = 0; jj < 4; ++jj)
                acc[jj] += __shfl(hlo[jj], ks, 64) * t4;
        }
#pragma unroll
        for (int i = 16; i < 32; ++i) {      // k = 4*i + p, k >= 64
            uint2 pk = *(const uint2*)(Tb + i * 256 + p * 64 + o4);
            f32x4 t4 = { bf16_lo(pk.x), bf16_hi(pk.x), bf16_lo(pk.y), bf16_hi(pk.y) };
            int ks = (i - 16) * 4 + p;
#pragma unroll
            for (int jj = 0; jj < 4; ++jj)
                acc[jj] += __shfl(hhi[jj], ks, 64) * t4;
        }
#pragma unroll
        for (int jj = 0; jj < 4; ++jj)
#pragma unroll
            for (int c = 0; c < 4; ++c) {
                acc[jj][c] += __shfl_xor(acc[jj][c], 16, 64);
                acc[jj][c] += __shfl_xor(acc[jj][c], 32, 64);
            }
        if (lane < 16) {
            uint2 bk = *(const uint2*)(Tb + 8192 + o4);
            f32x4 b4 = { bf16_lo(bk.x), bf16_hi(bk.x), bf16_lo(bk.y), bf16_hi(bk.y) };
#pragma unroll
            for (int jj = 0; jj < 4; ++jj)
                if (j0 + jj < end)
                    *(f32x4*)(msg + (size_t)e[jj] * 64 + o4) = acc[jj] + b4;
        }
    }
}

// per dst-node wave: out[d] = relu(sum msg + cbias); atomic-free
__global__ void k_agg(const float* __restrict__ msg, const int* __restrict__ offD,
                      const int* __restrict__ permD, const float* __restrict__ cbias,
                      float* __restrict__ outb, unsigned short* __restrict__ outbf, int n_nodes) {
    int wave = threadIdx.x >> 6, lane = threadIdx.x & 63;
    int d = blockIdx.x * 4 + wave;
    if (d >= n_nodes) return;
    float acc = 0.f;
    int end = offD[d + 1];
    for (int j = offD[d]; j < end; ++j)
        acc += msg[(size_t)permD[j] * 64 + lane];
    float v = fmaxf(acc + cbias[lane], 0.f);
    outb[(size_t)d * 64 + lane] = v;
    outbf[(size_t)d * 64 + lane] = f32_to_bf16(v);
}

// grid MUST be 64 blocks (row stride 256 hardcoded)
__global__ void k_bn_stats(const float* __restrict__ out, float* __restrict__ stat, int n_nodes) {
    __shared__ float s1[256], s2[256];
    int tid = threadIdx.x;
    int f = tid & 63, g = tid >> 6;
    float sum = 0.f, ss = 0.f;
    for (int r = blockIdx.x * 4 + g; r < n_nodes; r += 256) {
        float v = out[r * HDIM + f];
        sum += v; ss += v * v;
    }
    s1[tid] = sum; s2[tid] = ss;
    __syncthreads();
    if (tid < 64) {
        float A = s1[tid] + s1[64 + tid] + s1[128 + tid] + s1[192 + tid];
        float B = s2[tid] + s2[64 + tid] + s2[128 + tid] + s2[192 + tid];
        atomicAdd(&stat[tid], A);
        atomicAdd(&stat[64 + tid], B);
    }
}

__global__ void k_bn_final(const float* __restrict__ stat, const float* __restrict__ gamma,
                           const float* __restrict__ beta, float* __restrict__ sc, int n_nodes) {
    int f = threadIdx.x;
    if (f >= 64) return;
    float mean = stat[f] / n_nodes;
    float var  = stat[64 + f] / n_nodes - mean * mean;   // population var
    float inv  = rsqrtf(var + 1e-5f);
    float scale = gamma[f] * inv;
    sc[f] = scale;
    sc[64 + f] = beta[f] - mean * scale;
}

__global__ void k_bn_apply(const float* __restrict__ out, const float* __restrict__ sc,
                           float* __restrict__ y, int n) {
    int t = blockIdx.x * 256 + threadIdx.x;
    if (t >= n) return;
    int f = t & 63;
    y[t] = out[t] * sc[f] + sc[64 + f];
}

extern "C" void kernel_launch(void* const* d_in, const int* in_sizes, int n_in,
                              void* d_out, int out_size, void* d_ws, size_t ws_size,
                              hipStream_t stream) {
    const float* nf    = (const float*)d_in[0];
    const float* ef    = (const float*)d_in[1];
    const int*   src   = (const int*)d_in[2];
    const int*   dst   = (const int*)d_in[3];
    const float* W0    = (const float*)d_in[4];
    const float* b0    = (const float*)d_in[5];
    const float* We1   = (const float*)d_in[6];
    const float* be1   = (const float*)d_in[7];
    const float* We2   = (const float*)d_in[8];
    const float* be2   = (const float*)d_in[9];
    const float* cbias = (const float*)d_in[10];
    const float* gamma = (const float*)d_in[11];
    const float* beta  = (const float*)d_in[12];
    (void)n_in; (void)out_size;

    int n_nodes = in_sizes[0] / DIN;   // 10000
    int n_edges = in_sizes[2];         // 100000

    char* ws = (char*)d_ws;
    size_t off = 0;
    auto carve = [&](size_t bytes) -> void* {
        void* p = ws + off;
        off = (off + bytes + 255) & ~(size_t)255;
        return p;
    };
    // fixed carves first; T takes the remainder (ws_size = 256 MiB per R1 evidence)
    float*          h     = (float*)carve((size_t)n_edges * EHID * 4);      // 51.2 MB
    float*          msg   = (float*)carve((size_t)n_edges * 64 * 4);        // 25.6 MB
    float*          outb  = (float*)carve((size_t)n_nodes * HDIM * 4);
    unsigned short* outbf = (unsigned short*)carve((size_t)n_nodes * HDIM * 2);
    unsigned short* BmatT = (unsigned short*)carve((size_t)TC * 64 * 2);
    int*            offS  = (int*)carve((size_t)(n_nodes + 1) * 4);
    int*            offD  = (int*)carve((size_t)(n_nodes + 1) * 4);
    int*            curS  = (int*)carve((size_t)n_nodes * 4);
    int*            curD  = (int*)carve((size_t)n_nodes * 4);
    int*            permS = (int*)carve((size_t)n_edges * 4);
    int*            permD = (int*)carve((size_t)n_edges * 4);
    float*          stat  = (float*)carve(128 * 4 + (size_t)2 * n_nodes * 4); // stat + cntS + cntD
    int*            cntS  = (int*)(stat + 128);
    int*            cntD  = cntS + n_nodes;
    float*          sc    = (float*)carve(128 * 4);
    unsigned short* T     = (unsigned short*)(ws + off);
    size_t avail = ws_size > off ? ws_size - off : 0;
    long tcap = (long)(avail / ((size_t)TC * 2));   // node rows of bf16 T that fit
    if (tcap > n_nodes) tcap = n_nodes;
    if (tcap < 64) tcap = 64;                       // last-resort guard

    hipMemsetAsync(stat, 0, 128 * 4 + (size_t)2 * n_nodes * 4, stream);

    k_node_mlp<<<dim3((n_nodes + 3) / 4), 256, 0, stream>>>(nf, W0, b0, outb, outbf, n_nodes);
    k_edge_mlp<<<dim3((n_edges + 1) / 2), 256, 0, stream>>>(ef, We1, be1, h, n_edges);
    k_bmat<<<dim3((TC * 64 + 255) / 256), 256, 0, stream>>>(We2, be2, BmatT);
    k_hist<<<dim3((n_edges + 255) / 256), 256, 0, stream>>>(src, dst, cntS, cntD, n_edges);
    k_scan<<<dim3(2), 256, 0, stream>>>(cntS, cntD, offS, offD, curS, curD, n_nodes, n_edges);
    k_perm<<<dim3((n_edges + 255) / 256), 256, 0, stream>>>(src, dst, curS, curD, permS, permD, n_edges);

    for (int step = 0; step < STEPS; ++step) {
        for (long n0 = 0; n0 < n_nodes; n0 += tcap) {
            long n1 = n0 + tcap; if (n1 > n_nodes) n1 = n_nodes;
            long cnt = n1 - n0;
            k_T<<<dim3((cnt + 63) / 64, (TC + 255) / 256), 256, 0, stream>>>(
                outbf, BmatT, T, (int)n0, (int)n1);
            k_msg<<<dim3((cnt + 3) / 4), 256, 0, stream>>>(
                h, T, offS, permS, msg, (int)n0, (int)n1);
        }
        k_agg<<<dim3((n_nodes + 3) / 4), 256, 0, stream>>>(msg, offD, permD, cbias, outb, outbf, n_nodes);
    }

    k_bn_stats<<<dim3(64), 256, 0, stream>>>(outb, stat, n_nodes);
    k_bn_final<<<dim3(1), 64, 0, stream>>>(stat, gamma, beta, sc, n_nodes);
    k_bn_apply<<<dim3((n_nodes * HDIM + 255) / 256), 256, 0, stream>>>(
        outb, sc, (float*)d_out, n_nodes * HDIM);
}

// Round 4
// 940.404 us; speedup vs baseline: 2.5935x; 1.1383x over previous
//
#include <hip/hip_runtime.h>
#include <stdint.h>

#define DIN   64
#define HDIM  64
#define EIN   16
#define EHID  128     // edge hidden width
#define HH    4096    // HDIM*HDIM
#define TC    8256    // T columns: 8192 (k*64+o) + 64 bias cols (x@be2-term)
#define STEPS 3

typedef short bf16x8 __attribute__((ext_vector_type(8)));
typedef float f32x4  __attribute__((ext_vector_type(4)));

__device__ __forceinline__ unsigned short f32_to_bf16(float f) {
    union { float f; uint32_t u; } v; v.f = f;
    uint32_t r = v.u + 0x7fffu + ((v.u >> 16) & 1u);   // RNE
    return (unsigned short)(r >> 16);
}
__device__ __forceinline__ float bf16_lo(uint32_t u) {
    union { uint32_t u; float f; } v; v.u = u << 16; return v.f;
}
__device__ __forceinline__ float bf16_hi(uint32_t u) {
    union { uint32_t u; float f; } v; v.u = u & 0xffff0000u; return v.f;
}

// out[n,o] = relu(n_feat[n,:]@W0[:,o]+b0[o]); writes f32 + bf16 copies
__global__ void k_node_mlp(const float* __restrict__ nf, const float* __restrict__ W0,
                           const float* __restrict__ b0, float* __restrict__ outb,
                           unsigned short* __restrict__ outbf, int n_nodes) {
    __shared__ float w0s[DIN * HDIM];
    int tid = threadIdx.x;
    for (int i = tid; i < DIN * HDIM; i += 256) w0s[i] = W0[i];
    __syncthreads();
    int node = blockIdx.x * 4 + (tid >> 6);
    int o = tid & 63;
    if (node >= n_nodes) return;
    float xr = nf[node * DIN + o];
    float acc = b0[o];
#pragma unroll 8
    for (int i = 0; i < DIN; ++i)
        acc += __shfl(xr, i, 64) * w0s[i * HDIM + o];
    float v = fmaxf(acc, 0.f);
    outb[node * HDIM + o] = v;
    outbf[node * HDIM + o] = f32_to_bf16(v);
}

// h[e,c] = relu(e_feat[e,:]@We1[:,c]+be1[c]) -> bf16 (halves bytes; k_msg reads packed pairs)
__global__ void k_edge_mlp(const float* __restrict__ ef, const float* __restrict__ We1,
                           const float* __restrict__ be1, unsigned short* __restrict__ h, int n_edges) {
    int tid = threadIdx.x;
    int e = blockIdx.x * 2 + (tid >> 7);
    int c = tid & 127;
    if (e >= n_edges) return;
    float acc = be1[c];
    const float* x = ef + (size_t)e * EIN;
#pragma unroll
    for (int i = 0; i < EIN; ++i) acc += x[i] * We1[i * EHID + c];
    h[(size_t)e * EHID + c] = f32_to_bf16(fmaxf(acc, 0.f));
}

// BmatT[c_mfma][i] with column permutation baked in:
// mfma-col c within its 64-group g=c&63 (g = nt*16+r) maps to memory col 4r+nt,
// so the k_T epilogue can pack 4 nt-values into one ushort4 store.
// semantic col m: m<8192 -> B[i][m]=We2[m>>6][i*64+(m&63)]; m>=8192 -> be2[i*64+(m&63)]
__global__ void k_bmat(const float* __restrict__ We2, const float* __restrict__ be2,
                       unsigned short* __restrict__ BmatT) {
    int t = blockIdx.x * 256 + threadIdx.x;
    if (t >= TC * 64) return;
    int c = t >> 6, i = t & 63;
    int g = c & 63;
    int m = (c & ~63) + 4 * (g & 15) + (g >> 4);
    float v = (m < 8192) ? We2[(m >> 6) * HH + i * 64 + (m & 63)]
                         : be2[i * 64 + (m & 63)];
    BmatT[t] = f32_to_bf16(v);
}

// T[n, m] = sum_i x[n,i]*B[i,m], bf16 out, natural layout m = k*64+o (+bias block).
// wg: 64 nodes x 256 cols; wave: 64x64 via 4x4 16x16x32 bf16 MFMA tiles.
// Epilogue: lane packs nt=0..3 (mem cols cb+4r..cb+4r+3) into one 8-B store.
__global__ void k_T(const unsigned short* __restrict__ outbf, const unsigned short* __restrict__ BmatT,
                    unsigned short* __restrict__ T, int n0, int n1) {
    int wave = threadIdx.x >> 6, lane = threadIdx.x & 63;
    int r = lane & 15, q = lane >> 4;
    int eb = n0 + blockIdx.x * 64;
    int cb = blockIdx.y * 256 + wave * 64;
    f32x4 acc[4][4] = {};
#pragma unroll
    for (int s = 0; s < 2; ++s) {            // K = 64 = 2*32
        bf16x8 afr[4], bfr[4];
#pragma unroll
        for (int mt = 0; mt < 4; ++mt) {
            int e = eb + mt * 16 + r;
            if (e >= n1) e = n1 - 1;
            afr[mt] = *(const bf16x8*)(outbf + (size_t)e * 64 + s * 32 + q * 8);
        }
#pragma unroll
        for (int nt = 0; nt < 4; ++nt) {
            int c = cb + nt * 16 + r;
            if (c >= TC) c = 0;              // clamped load; store guarded
            bfr[nt] = *(const bf16x8*)(BmatT + (size_t)c * 64 + s * 32 + q * 8);
        }
#pragma unroll
        for (int mt = 0; mt < 4; ++mt)
#pragma unroll
            for (int nt = 0; nt < 4; ++nt)
                acc[mt][nt] = __builtin_amdgcn_mfma_f32_16x16x32_bf16(afr[mt], bfr[nt], acc[mt][nt], 0, 0, 0);
    }
    if (cb >= TC) return;
#pragma unroll
    for (int mt = 0; mt < 4; ++mt)
#pragma unroll
        for (int rg = 0; rg < 4; ++rg) {
            int n = eb + mt * 16 + q * 4 + rg;     // C/D: col=lane&15, row=quad*4+reg
            if (n >= n1) continue;
            ushort4 pk;
            pk.x = f32_to_bf16(acc[mt][0][rg]);
            pk.y = f32_to_bf16(acc[mt][1][rg]);
            pk.z = f32_to_bf16(acc[mt][2][rg]);
            pk.w = f32_to_bf16(acc[mt][3][rg]);
            *(ushort4*)(T + (size_t)(n - n0) * TC + cb + 4 * r) = pk;
        }
}

// histogram src and dst
__global__ void k_hist(const int* __restrict__ src, const int* __restrict__ dst,
                       int* __restrict__ cntS, int* __restrict__ cntD, int n_edges) {
    int e = blockIdx.x * 256 + threadIdx.x;
    if (e >= n_edges) return;
    atomicAdd(&cntS[src[e]], 1);
    atomicAdd(&cntD[dst[e]], 1);
}

// exclusive prefix sum (one block per array; blockIdx.x: 0=S, 1=D)
__global__ void k_scan(const int* __restrict__ cntS, const int* __restrict__ cntD,
                       int* __restrict__ offS, int* __restrict__ offD,
                       int* __restrict__ curS, int* __restrict__ curD, int n, int total) {
    const int* cnt = blockIdx.x ? cntD : cntS;
    int* off = blockIdx.x ? offD : offS;
    int* cur = blockIdx.x ? curD : curS;
    __shared__ int part[256];
    int tid = threadIdx.x;
    int chunk = (n + 255) / 256;
    int c0 = tid * chunk, c1 = c0 + chunk; if (c1 > n) c1 = n; if (c0 > n) c0 = n;
    int s = 0;
    for (int i = c0; i < c1; ++i) s += cnt[i];
    part[tid] = s;
    __syncthreads();
    for (int st = 1; st < 256; st <<= 1) {
        int v = (tid >= st) ? part[tid - st] : 0;
        __syncthreads();
        part[tid] += v;
        __syncthreads();
    }
    int run = tid ? part[tid - 1] : 0;
    for (int i = c0; i < c1; ++i) { off[i] = run; cur[i] = run; run += cnt[i]; }
    if (tid == 0) off[n] = total;
}

__global__ void k_perm(const int* __restrict__ src, const int* __restrict__ dst,
                       int* __restrict__ curS, int* __restrict__ curD,
                       int* __restrict__ permS, int* __restrict__ permD, int n_edges) {
    int e = blockIdx.x * 256 + threadIdx.x;
    if (e >= n_edges) return;
    permS[atomicAdd(&curS[src[e]], 1)] = e;
    permD[atomicAdd(&curD[dst[e]], 1)] = e;
}

// per src-node wave: msg[e,o] = sum_k h[e,k]*T[n,k*64+o] + T[n,8192+o]
// T row (16.5 KB) register-cached ONCE per node: 32 uint2/lane (64 VGPRs).
// h packed bf16: lane's uint covers h[2*lane],h[2*lane+1]; h[e,k=4i+p] is
// lane 2i+(p>>1), half p&1 (lane-uniform select).
__global__ void k_msg(const unsigned short* __restrict__ h, const unsigned short* __restrict__ T,
                      const int* __restrict__ offS, const int* __restrict__ permS,
                      float* __restrict__ msg, int n0, int n1) {
    int wave = threadIdx.x >> 6, lane = threadIdx.x & 63;
    int n = n0 + blockIdx.x * 4 + wave;
    if (n >= n1) return;
    int beg = offS[n], end = offS[n + 1];
    if (beg == end) return;
    int p = lane >> 4, o4 = (lane & 15) * 4;
    const unsigned short* Tb = T + (size_t)(n - n0) * TC;
    uint2 tr[32];
#pragma unroll
    for (int i = 0; i < 32; ++i)            // lane slice covers k=4i+p, o=o4..o4+3
        tr[i] = *(const uint2*)(Tb + i * 256 + p * 64 + o4);
    uint2 tb = *(const uint2*)(Tb + 8192 + o4);
    f32x4 b4 = { bf16_lo(tb.x), bf16_hi(tb.x), bf16_lo(tb.y), bf16_hi(tb.y) };
    for (int j0 = beg; j0 < end; j0 += 4) {
        int e[4]; int hp[4];
        f32x4 acc[4] = {};
#pragma unroll
        for (int jj = 0; jj < 4; ++jj) {
            int jc = (j0 + jj < end) ? j0 + jj : end - 1;
            e[jj] = permS[jc];
            hp[jj] = *(const int*)(h + (size_t)e[jj] * EHID + lane * 2);
        }
#pragma unroll
        for (int i = 0; i < 32; ++i) {
            f32x4 t4 = { bf16_lo(tr[i].x), bf16_hi(tr[i].x), bf16_lo(tr[i].y), bf16_hi(tr[i].y) };
            int sl = 2 * i + (p >> 1);
#pragma unroll
            for (int jj = 0; jj < 4; ++jj) {
                uint32_t hv = (uint32_t)__shfl(hp[jj], sl, 64);
                float hk = (p & 1) ? bf16_hi(hv) : bf16_lo(hv);
                acc[jj] += hk * t4;
            }
        }
#pragma unroll
        for (int jj = 0; jj < 4; ++jj)
#pragma unroll
            for (int c = 0; c < 4; ++c) {
                acc[jj][c] += __shfl_xor(acc[jj][c], 16, 64);
                acc[jj][c] += __shfl_xor(acc[jj][c], 32, 64);
            }
        if (lane < 16) {
#pragma unroll
            for (int jj = 0; jj < 4; ++jj)
                if (j0 + jj < end)
                    *(f32x4*)(msg + (size_t)e[jj] * 64 + o4) = acc[jj] + b4;
        }
    }
}

// per dst-node wave: out[d] = relu(sum msg + cbias); atomic-free
__global__ void k_agg(const float* __restrict__ msg, const int* __restrict__ offD,
                      const int* __restrict__ permD, const float* __restrict__ cbias,
                      float* __restrict__ outb, unsigned short* __restrict__ outbf, int n_nodes) {
    int wave = threadIdx.x >> 6, lane = threadIdx.x & 63;
    int d = blockIdx.x * 4 + wave;
    if (d >= n_nodes) return;
    float acc = 0.f;
    int end = offD[d + 1];
    for (int j = offD[d]; j < end; ++j)
        acc += msg[(size_t)permD[j] * 64 + lane];
    float v = fmaxf(acc + cbias[lane], 0.f);
    outb[(size_t)d * 64 + lane] = v;
    outbf[(size_t)d * 64 + lane] = f32_to_bf16(v);
}

// grid MUST be 64 blocks (row stride 256 hardcoded)
__global__ void k_bn_stats(const float* __restrict__ out, float* __restrict__ stat, int n_nodes) {
    __shared__ float s1[256], s2[256];
    int tid = threadIdx.x;
    int f = tid & 63, g = tid >> 6;
    float sum = 0.f, ss = 0.f;
    for (int r = blockIdx.x * 4 + g; r < n_nodes; r += 256) {
        float v = out[r * HDIM + f];
        sum += v; ss += v * v;
    }
    s1[tid] = sum; s2[tid] = ss;
    __syncthreads();
    if (tid < 64) {
        float A = s1[tid] + s1[64 + tid] + s1[128 + tid] + s1[192 + tid];
        float B = s2[tid] + s2[64 + tid] + s2[128 + tid] + s2[192 + tid];
        atomicAdd(&stat[tid], A);
        atomicAdd(&stat[64 + tid], B);
    }
}

__global__ void k_bn_final(const float* __restrict__ stat, const float* __restrict__ gamma,
                           const float* __restrict__ beta, float* __restrict__ sc, int n_nodes) {
    int f = threadIdx.x;
    if (f >= 64) return;
    float mean = stat[f] / n_nodes;
    float var  = stat[64 + f] / n_nodes - mean * mean;   // population var
    float inv  = rsqrtf(var + 1e-5f);
    float scale = gamma[f] * inv;
    sc[f] = scale;
    sc[64 + f] = beta[f] - mean * scale;
}

__global__ void k_bn_apply(const float* __restrict__ out, const float* __restrict__ sc,
                           float* __restrict__ y, int n) {
    int t = blockIdx.x * 256 + threadIdx.x;
    if (t >= n) return;
    int f = t & 63;
    y[t] = out[t] * sc[f] + sc[64 + f];
}

extern "C" void kernel_launch(void* const* d_in, const int* in_sizes, int n_in,
                              void* d_out, int out_size, void* d_ws, size_t ws_size,
                              hipStream_t stream) {
    const float* nf    = (const float*)d_in[0];
    const float* ef    = (const float*)d_in[1];
    const int*   src   = (const int*)d_in[2];
    const int*   dst   = (const int*)d_in[3];
    const float* W0    = (const float*)d_in[4];
    const float* b0    = (const float*)d_in[5];
    const float* We1   = (const float*)d_in[6];
    const float* be1   = (const float*)d_in[7];
    const float* We2   = (const float*)d_in[8];
    const float* be2   = (const float*)d_in[9];
    const float* cbias = (const float*)d_in[10];
    const float* gamma = (const float*)d_in[11];
    const float* beta  = (const float*)d_in[12];
    (void)n_in; (void)out_size;

    int n_nodes = in_sizes[0] / DIN;   // 10000
    int n_edges = in_sizes[2];         // 100000

    char* ws = (char*)d_ws;
    size_t off = 0;
    auto carve = [&](size_t bytes) -> void* {
        void* p = ws + off;
        off = (off + bytes + 255) & ~(size_t)255;
        return p;
    };
    // fixed carves ~57 MB; T takes the remainder (ws 256 MiB -> tcap = full 10000)
    unsigned short* h     = (unsigned short*)carve((size_t)n_edges * EHID * 2);  // 25.6 MB
    float*          msg   = (float*)carve((size_t)n_edges * 64 * 4);             // 25.6 MB
    float*          outb  = (float*)carve((size_t)n_nodes * HDIM * 4);
    unsigned short* outbf = (unsigned short*)carve((size_t)n_nodes * HDIM * 2);
    unsigned short* BmatT = (unsigned short*)carve((size_t)TC * 64 * 2);
    int*            offS  = (int*)carve((size_t)(n_nodes + 1) * 4);
    int*            offD  = (int*)carve((size_t)(n_nodes + 1) * 4);
    int*            curS  = (int*)carve((size_t)n_nodes * 4);
    int*            curD  = (int*)carve((size_t)n_nodes * 4);
    int*            permS = (int*)carve((size_t)n_edges * 4);
    int*            permD = (int*)carve((size_t)n_edges * 4);
    float*          stat  = (float*)carve(128 * 4 + (size_t)2 * n_nodes * 4); // stat + cntS + cntD
    int*            cntS  = (int*)(stat + 128);
    int*            cntD  = cntS + n_nodes;
    float*          sc    = (float*)carve(128 * 4);
    unsigned short* T     = (unsigned short*)(ws + off);
    size_t avail = ws_size > off ? ws_size - off : 0;
    long tcap = (long)(avail / ((size_t)TC * 2));   // node rows of bf16 T that fit
    if (tcap > n_nodes) tcap = n_nodes;
    if (tcap < 64) tcap = 64;                       // last-resort guard

    hipMemsetAsync(stat, 0, 128 * 4 + (size_t)2 * n_nodes * 4, stream);

    k_node_mlp<<<dim3((n_nodes + 3) / 4), 256, 0, stream>>>(nf, W0, b0, outb, outbf, n_nodes);
    k_edge_mlp<<<dim3((n_edges + 1) / 2), 256, 0, stream>>>(ef, We1, be1, h, n_edges);
    k_bmat<<<dim3((TC * 64 + 255) / 256), 256, 0, stream>>>(We2, be2, BmatT);
    k_hist<<<dim3((n_edges + 255) / 256), 256, 0, stream>>>(src, dst, cntS, cntD, n_edges);
    k_scan<<<dim3(2), 256, 0, stream>>>(cntS, cntD, offS, offD, curS, curD, n_nodes, n_edges);
    k_perm<<<dim3((n_edges + 255) / 256), 256, 0, stream>>>(src, dst, curS, curD, permS, permD, n_edges);

    for (int step = 0; step < STEPS; ++step) {
        for (long n0 = 0; n0 < n_nodes; n0 += tcap) {
            long n1 = n0 + tcap; if (n1 > n_nodes) n1 = n_nodes;
            long cnt = n1 - n0;
            k_T<<<dim3((cnt + 63) / 64, (TC + 255) / 256), 256, 0, stream>>>(
                outbf, BmatT, T, (int)n0, (int)n1);
            k_msg<<<dim3((cnt + 3) / 4), 256, 0, stream>>>(
                h, T, offS, permS, msg, (int)n0, (int)n1);
        }
        k_agg<<<dim3((n_nodes + 3) / 4), 256, 0, stream>>>(msg, offD, permD, cbias, outb, outbf, n_nodes);
    }

    k_bn_stats<<<dim3(64), 256, 0, stream>>>(outb, stat, n_nodes);
    k_bn_final<<<dim3(1), 64, 0, stream>>>(stat, gamma, beta, sc, n_nodes);
    k_bn_apply<<<dim3((n_nodes * HDIM + 255) / 256), 256, 0, stream>>>(
        outb, sc, (float*)d_out, n_nodes * HDIM);
}

// Round 5
// 509.121 us; speedup vs baseline: 4.7905x; 1.8471x over previous
//
#include <hip/hip_runtime.h>
#include <stdint.h>

#define DIN   64
#define HDIM  64
#define EIN   16
#define EHID  128     // edge hidden width
#define HH    4096    // HDIM*HDIM
#define TC    8256    // T cols: 8192 (layout s*2048 + o*32 + (k&31)) + 64 bias
#define STEPS 3

typedef short bf16x8 __attribute__((ext_vector_type(8)));
typedef float f32x4  __attribute__((ext_vector_type(4)));

__device__ __forceinline__ unsigned short f32_to_bf16(float f) {
    union { float f; uint32_t u; } v; v.f = f;
    uint32_t r = v.u + 0x7fffu + ((v.u >> 16) & 1u);   // RNE
    return (unsigned short)(r >> 16);
}
__device__ __forceinline__ float bfu_to_f(unsigned short u) {
    union { uint32_t u; float f; } v; v.u = (uint32_t)u << 16; return v.f;
}

// out[n,o] = relu(n_feat[n,:]@W0[:,o]+b0[o]); writes f32 + bf16 copies
__global__ void k_node_mlp(const float* __restrict__ nf, const float* __restrict__ W0,
                           const float* __restrict__ b0, float* __restrict__ outb,
                           unsigned short* __restrict__ outbf, int n_nodes) {
    __shared__ float w0s[DIN * HDIM];
    int tid = threadIdx.x;
    for (int i = tid; i < DIN * HDIM; i += 256) w0s[i] = W0[i];
    __syncthreads();
    int node = blockIdx.x * 4 + (tid >> 6);
    int o = tid & 63;
    if (node >= n_nodes) return;
    float xr = nf[node * DIN + o];
    float acc = b0[o];
#pragma unroll 8
    for (int i = 0; i < DIN; ++i)
        acc += __shfl(xr, i, 64) * w0s[i * HDIM + o];
    float v = fmaxf(acc, 0.f);
    outb[node * HDIM + o] = v;
    outbf[node * HDIM + o] = f32_to_bf16(v);
}

// h[e,c] = relu(e_feat[e,:]@We1[:,c]+be1[c]) -> bf16 row-major [E][128]
__global__ void k_edge_mlp(const float* __restrict__ ef, const float* __restrict__ We1,
                           const float* __restrict__ be1, unsigned short* __restrict__ h, int n_edges) {
    int tid = threadIdx.x;
    int e = blockIdx.x * 2 + (tid >> 7);
    int c = tid & 127;
    if (e >= n_edges) return;
    float acc = be1[c];
    const float* x = ef + (size_t)e * EIN;
#pragma unroll
    for (int i = 0; i < EIN; ++i) acc += x[i] * We1[i * EHID + c];
    h[(size_t)e * EHID + c] = f32_to_bf16(fmaxf(acc, 0.f));
}

// BmatT[c_mfma][i]: two permutations baked in.
// (1) k_T epilogue packing: mfma-col c, g=c&63 -> memory col m = (c&~63)+4*(g&15)+(g>>4)
// (2) T'' B-fragment layout: m<8192 -> s=m>>11, k=s*32+(m&31), o=(m>>5)&63,
//     value = We2[k*4096 + i*64 + o]; m>=8192 -> be2[i*64+(m-8192)]
__global__ void k_bmat(const float* __restrict__ We2, const float* __restrict__ be2,
                       unsigned short* __restrict__ BmatT) {
    int t = blockIdx.x * 256 + threadIdx.x;
    if (t >= TC * 64) return;
    int c = t >> 6, i = t & 63;
    int g = c & 63;
    int m = (c & ~63) + 4 * (g & 15) + (g >> 4);
    float v;
    if (m < 8192) {
        int k = ((m >> 11) << 5) | (m & 31);
        int o = (m >> 5) & 63;
        v = We2[k * HH + i * 64 + o];
    } else {
        v = be2[i * 64 + (m - 8192)];
    }
    BmatT[t] = f32_to_bf16(v);
}

// T[n, m] = sum_i x[n,i]*B[i,m], bf16 out in T'' layout.
// GRID SWAPPED: x = col-tile (writes of same node rows run concurrently ->
// dense 16.5-KB row writes), y = node-tile.
__global__ void k_T(const unsigned short* __restrict__ outbf, const unsigned short* __restrict__ BmatT,
                    unsigned short* __restrict__ T, int n0, int n1) {
    int wave = threadIdx.x >> 6, lane = threadIdx.x & 63;
    int r = lane & 15, q = lane >> 4;
    int eb = n0 + blockIdx.y * 64;
    int cb = blockIdx.x * 256 + wave * 64;
    f32x4 acc[4][4] = {};
#pragma unroll
    for (int s = 0; s < 2; ++s) {            // K = 64 = 2*32
        bf16x8 afr[4], bfr[4];
#pragma unroll
        for (int mt = 0; mt < 4; ++mt) {
            int e = eb + mt * 16 + r;
            if (e >= n1) e = n1 - 1;
            afr[mt] = *(const bf16x8*)(outbf + (size_t)e * 64 + s * 32 + q * 8);
        }
#pragma unroll
        for (int nt = 0; nt < 4; ++nt) {
            int c = cb + nt * 16 + r;
            if (c >= TC) c = 0;              // clamped load; store guarded
            bfr[nt] = *(const bf16x8*)(BmatT + (size_t)c * 64 + s * 32 + q * 8);
        }
#pragma unroll
        for (int mt = 0; mt < 4; ++mt)
#pragma unroll
            for (int nt = 0; nt < 4; ++nt)
                acc[mt][nt] = __builtin_amdgcn_mfma_f32_16x16x32_bf16(afr[mt], bfr[nt], acc[mt][nt], 0, 0, 0);
    }
    if (cb >= TC) return;
#pragma unroll
    for (int mt = 0; mt < 4; ++mt)
#pragma unroll
        for (int rg = 0; rg < 4; ++rg) {
            int n = eb + mt * 16 + q * 4 + rg;     // C/D: col=lane&15, row=quad*4+reg
            if (n >= n1) continue;
            ushort4 pk;
            pk.x = f32_to_bf16(acc[mt][0][rg]);
            pk.y = f32_to_bf16(acc[mt][1][rg]);
            pk.z = f32_to_bf16(acc[mt][2][rg]);
            pk.w = f32_to_bf16(acc[mt][3][rg]);
            *(ushort4*)(T + (size_t)(n - n0) * TC + cb + 4 * r) = pk;
        }
}

// histogram src and dst
__global__ void k_hist(const int* __restrict__ src, const int* __restrict__ dst,
                       int* __restrict__ cntS, int* __restrict__ cntD, int n_edges) {
    int e = blockIdx.x * 256 + threadIdx.x;
    if (e >= n_edges) return;
    atomicAdd(&cntS[src[e]], 1);
    atomicAdd(&cntD[dst[e]], 1);
}

// exclusive prefix sum (one block per array; blockIdx.x: 0=S, 1=D)
__global__ void k_scan(const int* __restrict__ cntS, const int* __restrict__ cntD,
                       int* __restrict__ offS, int* __restrict__ offD,
                       int* __restrict__ curS, int* __restrict__ curD, int n, int total) {
    const int* cnt = blockIdx.x ? cntD : cntS;
    int* off = blockIdx.x ? offD : offS;
    int* cur = blockIdx.x ? curD : curS;
    __shared__ int part[256];
    int tid = threadIdx.x;
    int chunk = (n + 255) / 256;
    int c0 = tid * chunk, c1 = c0 + chunk; if (c1 > n) c1 = n; if (c0 > n) c0 = n;
    int s = 0;
    for (int i = c0; i < c1; ++i) s += cnt[i];
    part[tid] = s;
    __syncthreads();
    for (int st = 1; st < 256; st <<= 1) {
        int v = (tid >= st) ? part[tid - st] : 0;
        __syncthreads();
        part[tid] += v;
        __syncthreads();
    }
    int run = tid ? part[tid - 1] : 0;
    for (int i = c0; i < c1; ++i) { off[i] = run; cur[i] = run; run += cnt[i]; }
    if (tid == 0) off[n] = total;
}

__global__ void k_perm(const int* __restrict__ src, const int* __restrict__ dst,
                       int* __restrict__ curS, int* __restrict__ curD,
                       int* __restrict__ permS, int* __restrict__ permD, int n_edges) {
    int e = blockIdx.x * 256 + threadIdx.x;
    if (e >= n_edges) return;
    permS[atomicAdd(&curS[src[e]], 1)] = e;
    permD[atomicAdd(&curD[dst[e]], 1)] = e;
}

// per src-node wave, MFMA: msg[tile of 16 edges][64 o] = h[edges, 0:128] @ T''[n]
// A-frag: lane(r,q) = h[e_r][s*32+q*8 .. +8] (16-B gather)
// B-frag: lane(r,q) = T''[n][s*2048 + (nt*16+r)*32 + q*8 .. +8] (1-KB coalesced/instr)
// C/D: col o = nt*16 + (lane&15), row = (lane>>4)*4 + rg
__global__ void k_msg(const unsigned short* __restrict__ h, const unsigned short* __restrict__ T,
                      const int* __restrict__ offS, const int* __restrict__ permS,
                      float* __restrict__ msg, int n0, int n1) {
    int wave = threadIdx.x >> 6, lane = threadIdx.x & 63;
    int n = n0 + blockIdx.x * 4 + wave;
    if (n >= n1) return;
    int beg = offS[n], end = offS[n + 1];
    if (beg == end) return;
    int r = lane & 15, q = lane >> 4;
    const unsigned short* Tb = T + (size_t)(n - n0) * TC;
    float bias[4];
#pragma unroll
    for (int nt = 0; nt < 4; ++nt)
        bias[nt] = bfu_to_f(Tb[8192 + nt * 16 + r]);
    for (int j0 = beg; j0 < end; j0 += 16) {
        int jc = j0 + r; if (jc >= end) jc = end - 1;
        int e = permS[jc];
        const unsigned short* he = h + (size_t)e * EHID;
        f32x4 acc[4] = {};
#pragma unroll
        for (int s = 0; s < 4; ++s) {        // K = 128 = 4*32
            bf16x8 afr = *(const bf16x8*)(he + s * 32 + q * 8);
#pragma unroll
            for (int nt = 0; nt < 4; ++nt) {
                bf16x8 bfr = *(const bf16x8*)(Tb + s * 2048 + (nt * 16 + r) * 32 + q * 8);
                acc[nt] = __builtin_amdgcn_mfma_f32_16x16x32_bf16(afr, bfr, acc[nt], 0, 0, 0);
            }
        }
#pragma unroll
        for (int rg = 0; rg < 4; ++rg) {
            int jr = j0 + q * 4 + rg;
            if (jr >= end) continue;
            int er = permS[jr];
#pragma unroll
            for (int nt = 0; nt < 4; ++nt)
                msg[(size_t)er * 64 + nt * 16 + r] = acc[nt][rg] + bias[nt];
        }
    }
}

// per dst-node wave: out[d] = relu(sum msg + cbias); atomic-free
__global__ void k_agg(const float* __restrict__ msg, const int* __restrict__ offD,
                      const int* __restrict__ permD, const float* __restrict__ cbias,
                      float* __restrict__ outb, unsigned short* __restrict__ outbf, int n_nodes) {
    int wave = threadIdx.x >> 6, lane = threadIdx.x & 63;
    int d = blockIdx.x * 4 + wave;
    if (d >= n_nodes) return;
    float acc = 0.f;
    int end = offD[d + 1];
    for (int j = offD[d]; j < end; ++j)
        acc += msg[(size_t)permD[j] * 64 + lane];
    float v = fmaxf(acc + cbias[lane], 0.f);
    outb[(size_t)d * 64 + lane] = v;
    outbf[(size_t)d * 64 + lane] = f32_to_bf16(v);
}

// grid MUST be 64 blocks (row stride 256 hardcoded)
__global__ void k_bn_stats(const float* __restrict__ out, float* __restrict__ stat, int n_nodes) {
    __shared__ float s1[256], s2[256];
    int tid = threadIdx.x;
    int f = tid & 63, g = tid >> 6;
    float sum = 0.f, ss = 0.f;
    for (int r = blockIdx.x * 4 + g; r < n_nodes; r += 256) {
        float v = out[r * HDIM + f];
        sum += v; ss += v * v;
    }
    s1[tid] = sum; s2[tid] = ss;
    __syncthreads();
    if (tid < 64) {
        float A = s1[tid] + s1[64 + tid] + s1[128 + tid] + s1[192 + tid];
        float B = s2[tid] + s2[64 + tid] + s2[128 + tid] + s2[192 + tid];
        atomicAdd(&stat[tid], A);
        atomicAdd(&stat[64 + tid], B);
    }
}

__global__ void k_bn_final(const float* __restrict__ stat, const float* __restrict__ gamma,
                           const float* __restrict__ beta, float* __restrict__ sc, int n_nodes) {
    int f = threadIdx.x;
    if (f >= 64) return;
    float mean = stat[f] / n_nodes;
    float var  = stat[64 + f] / n_nodes - mean * mean;   // population var
    float inv  = rsqrtf(var + 1e-5f);
    float scale = gamma[f] * inv;
    sc[f] = scale;
    sc[64 + f] = beta[f] - mean * scale;
}

__global__ void k_bn_apply(const float* __restrict__ out, const float* __restrict__ sc,
                           float* __restrict__ y, int n) {
    int t = blockIdx.x * 256 + threadIdx.x;
    if (t >= n) return;
    int f = t & 63;
    y[t] = out[t] * sc[f] + sc[64 + f];
}

extern "C" void kernel_launch(void* const* d_in, const int* in_sizes, int n_in,
                              void* d_out, int out_size, void* d_ws, size_t ws_size,
                              hipStream_t stream) {
    const float* nf    = (const float*)d_in[0];
    const float* ef    = (const float*)d_in[1];
    const int*   src   = (const int*)d_in[2];
    const int*   dst   = (const int*)d_in[3];
    const float* W0    = (const float*)d_in[4];
    const float* b0    = (const float*)d_in[5];
    const float* We1   = (const float*)d_in[6];
    const float* be1   = (const float*)d_in[7];
    const float* We2   = (const float*)d_in[8];
    const float* be2   = (const float*)d_in[9];
    const float* cbias = (const float*)d_in[10];
    const float* gamma = (const float*)d_in[11];
    const float* beta  = (const float*)d_in[12];
    (void)n_in; (void)out_size;

    int n_nodes = in_sizes[0] / DIN;   // 10000
    int n_edges = in_sizes[2];         // 100000

    char* ws = (char*)d_ws;
    size_t off = 0;
    auto carve = [&](size_t bytes) -> void* {
        void* p = ws + off;
        off = (off + bytes + 255) & ~(size_t)255;
        return p;
    };
    // fixed carves ~57 MB; T takes the remainder (ws 256 MiB -> tcap = full 10000)
    unsigned short* h     = (unsigned short*)carve((size_t)n_edges * EHID * 2);  // 25.6 MB
    float*          msg   = (float*)carve((size_t)n_edges * 64 * 4);             // 25.6 MB
    float*          outb  = (float*)carve((size_t)n_nodes * HDIM * 4);
    unsigned short* outbf = (unsigned short*)carve((size_t)n_nodes * HDIM * 2);
    unsigned short* BmatT = (unsigned short*)carve((size_t)TC * 64 * 2);
    int*            offS  = (int*)carve((size_t)(n_nodes + 1) * 4);
    int*            offD  = (int*)carve((size_t)(n_nodes + 1) * 4);
    int*            curS  = (int*)carve((size_t)n_nodes * 4);
    int*            curD  = (int*)carve((size_t)n_nodes * 4);
    int*            permS = (int*)carve((size_t)n_edges * 4);
    int*            permD = (int*)carve((size_t)n_edges * 4);
    float*          stat  = (float*)carve(128 * 4 + (size_t)2 * n_nodes * 4); // stat + cntS + cntD
    int*            cntS  = (int*)(stat + 128);
    int*            cntD  = cntS + n_nodes;
    float*          sc    = (float*)carve(128 * 4);
    unsigned short* T     = (unsigned short*)(ws + off);
    size_t avail = ws_size > off ? ws_size - off : 0;
    long tcap = (long)(avail / ((size_t)TC * 2));   // node rows of bf16 T that fit
    if (tcap > n_nodes) tcap = n_nodes;
    if (tcap < 64) tcap = 64;                       // last-resort guard

    hipMemsetAsync(stat, 0, 128 * 4 + (size_t)2 * n_nodes * 4, stream);

    k_node_mlp<<<dim3((n_nodes + 3) / 4), 256, 0, stream>>>(nf, W0, b0, outb, outbf, n_nodes);
    k_edge_mlp<<<dim3((n_edges + 1) / 2), 256, 0, stream>>>(ef, We1, be1, h, n_edges);
    k_bmat<<<dim3((TC * 64 + 255) / 256), 256, 0, stream>>>(We2, be2, BmatT);
    k_hist<<<dim3((n_edges + 255) / 256), 256, 0, stream>>>(src, dst, cntS, cntD, n_edges);
    k_scan<<<dim3(2), 256, 0, stream>>>(cntS, cntD, offS, offD, curS, curD, n_nodes, n_edges);
    k_perm<<<dim3((n_edges + 255) / 256), 256, 0, stream>>>(src, dst, curS, curD, permS, permD, n_edges);

    for (int step = 0; step < STEPS; ++step) {
        for (long n0 = 0; n0 < n_nodes; n0 += tcap) {
            long n1 = n0 + tcap; if (n1 > n_nodes) n1 = n_nodes;
            long cnt = n1 - n0;
            k_T<<<dim3((TC + 255) / 256, (cnt + 63) / 64), 256, 0, stream>>>(
                outbf, BmatT, T, (int)n0, (int)n1);
            k_msg<<<dim3((cnt + 3) / 4), 256, 0, stream>>>(
                h, T, offS, permS, msg, (int)n0, (int)n1);
        }
        k_agg<<<dim3((n_nodes + 3) / 4), 256, 0, stream>>>(msg, offD, permD, cbias, outb, outbf, n_nodes);
    }

    k_bn_stats<<<dim3(64), 256, 0, stream>>>(outb, stat, n_nodes);
    k_bn_final<<<dim3(1), 64, 0, stream>>>(stat, gamma, beta, sc, n_nodes);
    k_bn_apply<<<dim3((n_nodes * HDIM + 255) / 256), 256, 0, stream>>>(
        outb, sc, (float*)d_out, n_nodes * HDIM);
}